// Round 4
// baseline (242.431 us; speedup 1.0000x reference)
//
#include <hip/hip_runtime.h>

// PointPillarScatter: out[b][c][y][x] = feat[p][c] where coords[p]=(x,y,b), else 0.
// Strategy: build flat->pillar map in ws, then one OUTPUT-LINEAR gather pass:
// one thread per output float4, exactly like the 6.5 TB/s fill kernel, with a
// map lookup (L2-resident) + masked feat gathers folded in. Nontemporal stores
// keep the 219 MB output stream from evicting the 3.4 MB map out of L2.

#define C_CH 64

// Native Clang vector type: __builtin_nontemporal_store requires a vector of
// scalars, not HIP's HIP_vector_type<float,4> class.
typedef float nat_float4 __attribute__((ext_vector_type(4)));

__global__ void build_map_kernel(const int* __restrict__ coords, int n_pillars,
                                 const int* __restrict__ nx_p,
                                 const int* __restrict__ ny_p,
                                 int* __restrict__ map) {
    int p = blockIdx.x * blockDim.x + threadIdx.x;
    if (p >= n_pillars) return;
    const int nx = nx_p[0];
    const int ny = ny_p[0];
    const int x = coords[3 * p + 0];
    const int y = coords[3 * p + 1];
    const int b = coords[3 * p + 2];
    const long long m = (long long)b * (long long)(nx * ny) + (long long)y * nx + x;
    map[m] = p;
}

// One thread per output float4 (linear in b,c,y,x order — the fill pattern).
// t -> (bc, yx4): bc = t / plane4 (uniform divisor), b = bc/64, c = bc%64.
// Map int4 at [b*plane4 + yx4] gives 4 pillar ids; masked scalar feat loads
// fill the vector; one nontemporal dwordx4 store at linear address t.
__global__ void __launch_bounds__(256) gather_linear_kernel(
        const float* __restrict__ feat,
        const int* __restrict__ map,
        const int* __restrict__ nx_p,
        const int* __restrict__ ny_p,
        float* __restrict__ out, int n_out4) {
    const int t = blockIdx.x * blockDim.x + threadIdx.x;
    if (t >= n_out4) return;
    const int plane4 = (nx_p[0] * ny_p[0]) >> 2;   // uniform

    const int bc  = t / plane4;                    // = b*C + c
    const int yx4 = t - bc * plane4;
    const int b   = bc >> 6;                       // C == 64
    const int c   = bc & 63;

    const int4 pv = ((const int4*)map)[b * plane4 + yx4];

    nat_float4 v = {0.f, 0.f, 0.f, 0.f};
    if (pv.x >= 0) v.x = feat[pv.x * C_CH + c];
    if (pv.y >= 0) v.y = feat[pv.y * C_CH + c];
    if (pv.z >= 0) v.z = feat[pv.z * C_CH + c];
    if (pv.w >= 0) v.w = feat[pv.w * C_CH + c];

    __builtin_nontemporal_store(v, ((nat_float4*)out) + t);
}

// Fallback: direct scatter after zeroing the output (used only if ws is too
// small for the map, C != 64, or sizes aren't float4-divisible).
__global__ void direct_scatter_kernel(const float* __restrict__ feat,
                                      const int* __restrict__ coords,
                                      int n_pillars, int C,
                                      const int* __restrict__ nx_p,
                                      const int* __restrict__ ny_p,
                                      float* __restrict__ out) {
    const long long t = (long long)blockIdx.x * blockDim.x + threadIdx.x;
    if (t >= (long long)n_pillars * C) return;
    const int p = (int)(t / C);
    const int c = (int)(t - (long long)p * C);
    const int nx = nx_p[0];
    const int ny = ny_p[0];
    const int x = coords[3 * p + 0];
    const int y = coords[3 * p + 1];
    const int b = coords[3 * p + 2];
    const int plane = nx * ny;
    const size_t o = ((size_t)b * C + c) * (size_t)plane + (size_t)y * nx + x;
    out[o] = feat[(size_t)p * C + c];
}

extern "C" void kernel_launch(void* const* d_in, const int* in_sizes, int n_in,
                              void* d_out, int out_size, void* d_ws, size_t ws_size,
                              hipStream_t stream) {
    const float* feat   = (const float*)d_in[0];
    const int*   coords = (const int*)d_in[1];
    // d_in[2] = batch_size, d_in[3] = nx, d_in[4] = ny — device-resident
    // scalars, read inside the kernels where needed.
    const int* nx_p = (const int*)d_in[3];
    const int* ny_p = (const int*)d_in[4];
    float* out = (float*)d_out;

    const int n_pillars = in_sizes[1] / 3;
    const int C = in_sizes[0] / n_pillars;
    const int n_map = out_size / C;                 // B * NY * NX
    const size_t map_bytes = (size_t)n_map * sizeof(int);

    if (C == C_CH && (n_map & 3) == 0 && (out_size & 3) == 0 &&
        ws_size >= map_bytes) {
        int* map = (int*)d_ws;
        // 0xFF bytes -> every map entry == -1
        (void)hipMemsetAsync(map, 0xFF, map_bytes, stream);
        build_map_kernel<<<(n_pillars + 255) / 256, 256, 0, stream>>>(
            coords, n_pillars, nx_p, ny_p, map);
        const int n_out4 = out_size >> 2;
        gather_linear_kernel<<<(n_out4 + 255) / 256, 256, 0, stream>>>(
            feat, map, nx_p, ny_p, out, n_out4);
    } else {
        (void)hipMemsetAsync(out, 0, (size_t)out_size * sizeof(float), stream);
        const long long total = (long long)n_pillars * C;
        direct_scatter_kernel<<<(unsigned)((total + 255) / 256), 256, 0, stream>>>(
            feat, coords, n_pillars, C, nx_p, ny_p, out);
    }
}

// Round 5
// 233.417 us; speedup vs baseline: 1.0386x; 1.0386x over previous
//
#include <hip/hip_runtime.h>

// PointPillarScatter: out[b][c][y][x] = feat[p][c] where coords[p]=(x,y,b), else 0.
// Strategy: build flat->pillar map in ws, then one gather pass. Each thread
// owns 4 consecutive cells (one map int4) x 16 channels: 16 contiguous-per-wave
// temporal float4 stores (1 KB/wave-inst), float4-vectorized feature loads.

#define C_CH 64

// Native Clang vector type (needed for clean dwordx4 codegen + elementwise use).
typedef float nat_float4 __attribute__((ext_vector_type(4)));

__global__ void build_map_kernel(const int* __restrict__ coords, int n_pillars,
                                 const int* __restrict__ nx_p,
                                 const int* __restrict__ ny_p,
                                 int* __restrict__ map) {
    int p = blockIdx.x * blockDim.x + threadIdx.x;
    if (p >= n_pillars) return;
    const int nx = nx_p[0];
    const int ny = ny_p[0];
    const int x = coords[3 * p + 0];
    const int y = coords[3 * p + 1];
    const int b = coords[3 * p + 2];
    const long long m = (long long)b * (long long)(nx * ny) + (long long)y * nx + x;
    map[m] = p;
}

// n_thread = B * plane = n_map threads. Thread t -> (b, cgrp, i):
//   plane4 = plane/4; bcg = t / plane4; i = t - bcg*plane4; b = bcg>>2;
//   cgrp = bcg&3 (16-channel group). One map int4 at [b*plane4 + i];
//   per occupied pillar, 4 float4 feat loads (16 consecutive channels);
//   16 float4 stores at ((b*64 + cgrp*16 + k)*plane4 + i), k = 0..15.
// Consecutive lanes share (b,cgrp) and have consecutive i -> every store-inst
// covers 1 KB contiguous. All float4 indices fit in 32 bits.
__global__ void __launch_bounds__(256) gather16_kernel(
        const float* __restrict__ feat,
        const int* __restrict__ map,
        const int* __restrict__ nx_p,
        const int* __restrict__ ny_p,
        float* __restrict__ out, int n_thread) {
    const int t = blockIdx.x * blockDim.x + threadIdx.x;
    if (t >= n_thread) return;
    const int plane4 = (nx_p[0] * ny_p[0]) >> 2;   // uniform
    const int bcg = t / plane4;                    // b*4 + cgrp
    const int i   = t - bcg * plane4;
    const int b   = bcg >> 2;
    const int cgrp = bcg & 3;

    const int4 pv = ((const int4*)map)[b * plane4 + i];

    const nat_float4 zero = {0.f, 0.f, 0.f, 0.f};
    nat_float4 fx[4], fy[4], fz[4], fw[4];
#pragma unroll
    for (int k = 0; k < 4; ++k) { fx[k] = zero; fy[k] = zero; fz[k] = zero; fw[k] = zero; }

    const nat_float4* __restrict__ f4 = (const nat_float4*)feat;
    if (pv.x >= 0) {
        const nat_float4* r = f4 + pv.x * (C_CH / 4) + cgrp * 4;
        fx[0] = r[0]; fx[1] = r[1]; fx[2] = r[2]; fx[3] = r[3];
    }
    if (pv.y >= 0) {
        const nat_float4* r = f4 + pv.y * (C_CH / 4) + cgrp * 4;
        fy[0] = r[0]; fy[1] = r[1]; fy[2] = r[2]; fy[3] = r[3];
    }
    if (pv.z >= 0) {
        const nat_float4* r = f4 + pv.z * (C_CH / 4) + cgrp * 4;
        fz[0] = r[0]; fz[1] = r[1]; fz[2] = r[2]; fz[3] = r[3];
    }
    if (pv.w >= 0) {
        const nat_float4* r = f4 + pv.w * (C_CH / 4) + cgrp * 4;
        fw[0] = r[0]; fw[1] = r[1]; fw[2] = r[2]; fw[3] = r[3];
    }

    nat_float4* __restrict__ o = (nat_float4*)out + ((b * C_CH + cgrp * 16) * plane4 + i);
#pragma unroll
    for (int kk = 0; kk < 4; ++kk) {
#pragma unroll
        for (int j = 0; j < 4; ++j) {
            nat_float4 v;
            v.x = fx[kk][j]; v.y = fy[kk][j]; v.z = fz[kk][j]; v.w = fw[kk][j];
            o[(kk * 4 + j) * plane4] = v;      // temporal store — L2 write-back
        }
    }
}

// Fallback: direct scatter after zeroing the output (used only if ws is too
// small for the map, C != 64, or sizes aren't float4-divisible).
__global__ void direct_scatter_kernel(const float* __restrict__ feat,
                                      const int* __restrict__ coords,
                                      int n_pillars, int C,
                                      const int* __restrict__ nx_p,
                                      const int* __restrict__ ny_p,
                                      float* __restrict__ out) {
    const long long t = (long long)blockIdx.x * blockDim.x + threadIdx.x;
    if (t >= (long long)n_pillars * C) return;
    const int p = (int)(t / C);
    const int c = (int)(t - (long long)p * C);
    const int nx = nx_p[0];
    const int ny = ny_p[0];
    const int x = coords[3 * p + 0];
    const int y = coords[3 * p + 1];
    const int b = coords[3 * p + 2];
    const int plane = nx * ny;
    const size_t o = ((size_t)b * C + c) * (size_t)plane + (size_t)y * nx + x;
    out[o] = feat[(size_t)p * C + c];
}

extern "C" void kernel_launch(void* const* d_in, const int* in_sizes, int n_in,
                              void* d_out, int out_size, void* d_ws, size_t ws_size,
                              hipStream_t stream) {
    const float* feat   = (const float*)d_in[0];
    const int*   coords = (const int*)d_in[1];
    // d_in[2] = batch_size, d_in[3] = nx, d_in[4] = ny — device-resident
    // scalars, read inside the kernels where needed.
    const int* nx_p = (const int*)d_in[3];
    const int* ny_p = (const int*)d_in[4];
    float* out = (float*)d_out;

    const int n_pillars = in_sizes[1] / 3;
    const int C = in_sizes[0] / n_pillars;
    const int n_map = out_size / C;                 // B * NY * NX
    const size_t map_bytes = (size_t)n_map * sizeof(int);

    if (C == C_CH && (n_map & 3) == 0 && (out_size & 3) == 0 &&
        ws_size >= map_bytes) {
        int* map = (int*)d_ws;
        // 0xFF bytes -> every map entry == -1
        (void)hipMemsetAsync(map, 0xFF, map_bytes, stream);
        build_map_kernel<<<(n_pillars + 255) / 256, 256, 0, stream>>>(
            coords, n_pillars, nx_p, ny_p, map);
        const int n_thread = n_map;                 // (n_map/4 cell4s) * 4 cgrps
        gather16_kernel<<<(n_thread + 255) / 256, 256, 0, stream>>>(
            feat, map, nx_p, ny_p, out, n_thread);
    } else {
        (void)hipMemsetAsync(out, 0, (size_t)out_size * sizeof(float), stream);
        const long long total = (long long)n_pillars * C;
        direct_scatter_kernel<<<(unsigned)((total + 255) / 256), 256, 0, stream>>>(
            feat, coords, n_pillars, C, nx_p, ny_p, out);
    }
}